// Round 1
// baseline (1185.951 us; speedup 1.0000x reference)
//
#include <hip/hip_runtime.h>

// Problem constants (B=1 fixed)
#define S_LEN 2048
#define NH    32
#define NKV   8
#define DH    128
#define QDIM  4096   // NH*DH
#define KVDIM 1024   // NKV*DH
#define K2H   8192   // 2*HID
#define SCALE_F 0.08838834764831845f  // 128^-0.5

typedef __attribute__((ext_vector_type(8))) short short8;   // 8 bf16 (raw)
typedef __attribute__((ext_vector_type(4))) float f32x4;

__device__ __forceinline__ ushort f2bf(float f){
  union { float f; unsigned u; } x; x.f = f;
  unsigned r = (x.u + 0x7FFFu + ((x.u>>16)&1u)) >> 16;  // RNE, data has no NaN
  return (ushort)r;
}
__device__ __forceinline__ float bf2f(ushort h){
  union { unsigned u; float f; } x; x.u = ((unsigned)h)<<16; return x.f;
}

// ---------------- elementwise cast f32 -> bf16 (x4 vectorized) ----------------
__global__ void cast_f32_bf16(const float* __restrict__ in, ushort* __restrict__ out, int n4){
  int i = blockIdx.x*256 + threadIdx.x;
  if (i >= n4) return;
  float4 v = ((const float4*)in)[i];
  ushort4 o; o.x=f2bf(v.x); o.y=f2bf(v.y); o.z=f2bf(v.z); o.w=f2bf(v.w);
  ((ushort4*)out)[i] = o;
}

// ---------------- W [K][N] f32 -> WT [N][K] bf16 (32x32 LDS tile) ----------------
__global__ void transpose_cast(const float* __restrict__ in, ushort* __restrict__ out, int K, int N){
  __shared__ float tile[32][33];
  int n0 = blockIdx.x<<5, k0 = blockIdx.y<<5;
  int tx = threadIdx.x, ty = threadIdx.y;          // (32,8)
  #pragma unroll
  for (int j=0;j<4;++j)
    tile[ty+8*j][tx] = in[(size_t)(k0+ty+8*j)*N + n0 + tx];
  __syncthreads();
  #pragma unroll
  for (int j=0;j<4;++j)
    out[(size_t)(n0+ty+8*j)*K + k0 + tx] = f2bf(tile[tx][ty+8*j]);
}

// ---------------- cache_v0 [H][S][D] f32 -> v0t [H][D][S] bf16 ----------------
__global__ void transpose_v0(const float* __restrict__ v0, ushort* __restrict__ v0t){
  __shared__ float tile[32][33];
  int s0 = blockIdx.x<<5, d0 = blockIdx.y<<5, h = blockIdx.z;
  int tx = threadIdx.x, ty = threadIdx.y;          // (32,8)
  #pragma unroll
  for (int j=0;j<4;++j)
    tile[ty+8*j][tx] = v0[((size_t)h*S_LEN + s0+ty+8*j)*DH + d0 + tx];
  __syncthreads();
  #pragma unroll
  for (int j=0;j<4;++j)
    v0t[((size_t)h*DH + d0+ty+8*j)*S_LEN + s0 + tx] = f2bf(tile[tx][ty+8*j]);
}

// ---------------- RoPE + cast: pre [S][nh][128] f32 -> outb bf16 ----------------
__global__ void rope_cast(const float* __restrict__ pre, const int* __restrict__ pids,
                          ushort* __restrict__ outb, int nheads, int total){
  int idx = blockIdx.x*256 + threadIdx.x;
  if (idx >= total) return;
  int d = idx & 63; int r = idx >> 6;
  int h = r % nheads; int s = r / nheads;
  size_t base = ((size_t)s*nheads + h)*DH;
  float a = pre[base + d], b = pre[base + d + 64];
  float pos = (float)(pids[s] + 2);
  // inv_freq = 10000^(-d/64) = 2^(-d*log2(10000)/64)
  float ang = pos * exp2f(-(float)d * 0.20762050593046014f);
  float sn, cs; sincosf(ang, &sn, &cs);
  outb[base + d]      = f2bf(a*cs - b*sn);
  outb[base + d + 64] = f2bf(b*cs + a*sn);
}

// ---------------- bf16 GEMM: C[M][N] = A[M][K] @ Bt[N][K]^T, fp32 out ----------------
// 128x128 tile, BK=64, 4 waves (2x2), T2 XOR swizzle on 128B LDS rows.
__global__ __launch_bounds__(256) void gemm_bf16(
    const ushort* __restrict__ A, const ushort* __restrict__ Bt,
    float* __restrict__ C, int M, int N, int K)
{
  __shared__ __align__(16) ushort As[128*64];
  __shared__ __align__(16) ushort Bs[128*64];
  const int tid = threadIdx.x;
  const int w = tid>>6, lane = tid&63;
  const int wm = w>>1, wn = w&1;
  const int lg = lane>>4, lr = lane&15;
  const int m0 = blockIdx.y<<7, n0 = blockIdx.x<<7;
  f32x4 acc[4][4];
  #pragma unroll
  for (int mt=0;mt<4;++mt)
    #pragma unroll
    for (int nt=0;nt<4;++nt) acc[mt][nt] = (f32x4){0.f,0.f,0.f,0.f};

  for (int k0=0;k0<K;k0+=64){
    __syncthreads();
    #pragma unroll
    for (int i=0;i<4;++i){
      int c = i*256+tid; int row = c>>3, ch = c&7;      // 128 rows x 8 chunks(16B)
      short8 av = *(const short8*)(A + (size_t)(m0+row)*K + k0 + ch*8);
      *(short8*)((char*)As + row*128 + ((ch<<4) ^ ((row&7)<<4))) = av;
      short8 bv = *(const short8*)(Bt + (size_t)(n0+row)*K + k0 + ch*8);
      *(short8*)((char*)Bs + row*128 + ((ch<<4) ^ ((row&7)<<4))) = bv;
    }
    __syncthreads();
    #pragma unroll
    for (int ks=0;ks<2;++ks){
      short8 af[4], bfr[4];
      #pragma unroll
      for (int mt=0;mt<4;++mt){
        int row = (wm<<6)+(mt<<4)+lr;
        af[mt] = *(const short8*)((char*)As + row*128 + (((ks<<6)+(lg<<4)) ^ ((row&7)<<4)));
      }
      #pragma unroll
      for (int nt=0;nt<4;++nt){
        int row = (wn<<6)+(nt<<4)+lr;
        bfr[nt] = *(const short8*)((char*)Bs + row*128 + (((ks<<6)+(lg<<4)) ^ ((row&7)<<4)));
      }
      #pragma unroll
      for (int mt=0;mt<4;++mt)
        #pragma unroll
        for (int nt=0;nt<4;++nt)
          acc[mt][nt] = __builtin_amdgcn_mfma_f32_16x16x32_bf16(af[mt], bfr[nt], acc[mt][nt], 0,0,0);
    }
  }
  #pragma unroll
  for (int mt=0;mt<4;++mt)
    #pragma unroll
    for (int nt=0;nt<4;++nt)
      #pragma unroll
      for (int r=0;r<4;++r){
        int row = m0 + (wm<<6) + (mt<<4) + (lg<<2) + r;   // C/D: row=(lane>>4)*4+reg
        int col = n0 + (wn<<6) + (nt<<4) + lr;            //      col=lane&15
        C[(size_t)row*N + col] = acc[mt][nt][r];
      }
}

// ---------------- flash attention with 2 extra logit columns ----------------
// grid (S/64, H); block 256 = 4 waves; wave w owns q rows [q0+16w, q0+16w+16)
__global__ __launch_bounds__(256) void attn_kernel(
    const ushort* __restrict__ qb,   // [S][NH][DH] bf16 (roped)
    const ushort* __restrict__ kb,   // [S][NKV][DH] bf16 (roped)
    const float* __restrict__ k1c,   // [NH][S][DH]
    const float* __restrict__ v1c,   // [NH][S][DH]
    const float* __restrict__ k0c,   // [NH][S][DH]
    const ushort* __restrict__ v0t,  // [NH][DH][S] bf16
    const float* __restrict__ vpre,  // [S][NKV*DH]
    ushort* __restrict__ outb)       // [S][NH*DH] bf16
{
  __shared__ __align__(16) ushort Ks[64*128];   // [key][d], swizzled, 16KB
  __shared__ __align__(16) ushort Vs[128*64];   // [d][key], swizzled, 16KB
  __shared__ __align__(16) ushort Ps[4][16*64]; // per-wave P, swizzled, 8KB
  const int tid = threadIdx.x;
  const int w = tid>>6, lane = tid&63;
  const int lg = lane>>4, lr = lane&15;
  const int h = blockIdx.y, kvh = h>>2;
  const int q0 = blockIdx.x<<6, qbase = q0 + (w<<4);

  // Q fragments (A operand): row=lane&15, k=(lane>>4)*8 contiguous
  short8 qf[4];
  {
    int row = qbase + lr;
    const ushort* qr = qb + ((size_t)row*NH + h)*DH;
    #pragma unroll
    for (int ks=0;ks<4;++ks) qf[ks] = *(const short8*)(qr + ks*32 + lg*8);
  }

  // d1 = q . cache_k1[h,s] * scale ; d2 = q . k_roped[s,kvh] * scale (per q row)
  float d1v[4], d2v[4];
  #pragma unroll
  for (int r=0;r<4;++r){
    int row = qbase + (lg<<2) + r;
    const ushort* qr  = qb  + ((size_t)row*NH  + h  )*DH + lr*8;
    const float*  kr1 = k1c + ((size_t)h*S_LEN + row)*DH + lr*8;
    const ushort* kr2 = kb  + ((size_t)row*NKV + kvh)*DH + lr*8;
    float s1=0.f, s2=0.f;
    #pragma unroll
    for (int j=0;j<8;++j){
      float qv = bf2f(qr[j]);
      s1 = fmaf(qv, kr1[j], s1);
      s2 = fmaf(qv, bf2f(kr2[j]), s2);
    }
    #pragma unroll
    for (int mm=1;mm<16;mm<<=1){ s1 += __shfl_xor(s1,mm,64); s2 += __shfl_xor(s2,mm,64); }
    d1v[r] = s1*SCALE_F; d2v[r] = s2*SCALE_F;
  }

  f32x4 o[8];
  #pragma unroll
  for (int dt=0;dt<8;++dt) o[dt] = (f32x4){0.f,0.f,0.f,0.f};
  float mrow[4], lrow[4];
  #pragma unroll
  for (int r=0;r<4;++r){ mrow[r] = -1e30f; lrow[r] = 0.f; }

  const int ntiles = blockIdx.x + 1;   // causal: keys 0 .. q0+63
  for (int kt=0; kt<ntiles; ++kt){
    const int key0 = kt<<6;
    __syncthreads();
    // stage K0 tile [64 keys][128 d], fp32->bf16, swizzled 256B rows
    #pragma unroll
    for (int i=0;i<4;++i){
      int c = i*256 + tid;
      int krow = c>>4, ch = c&15;                        // 16 chunks of 16B per row
      const float* src = k0c + ((size_t)h*S_LEN + key0 + krow)*DH + ch*8;
      float4 fa = *(const float4*)src;
      float4 fb = *(const float4*)(src+4);
      short8 pk;
      pk[0]=(short)f2bf(fa.x); pk[1]=(short)f2bf(fa.y);
      pk[2]=(short)f2bf(fa.z); pk[3]=(short)f2bf(fa.w);
      pk[4]=(short)f2bf(fb.x); pk[5]=(short)f2bf(fb.y);
      pk[6]=(short)f2bf(fb.z); pk[7]=(short)f2bf(fb.w);
      *(short8*)((char*)Ks + krow*256 + ((ch<<4) ^ ((krow&7)<<4))) = pk;
    }
    // stage V0t tile [128 d][64 keys] bf16, swizzled 128B rows
    #pragma unroll
    for (int i=0;i<4;++i){
      int c = i*256 + tid;
      int drow = c>>3, ch = c&7;
      short8 vv = *(const short8*)(v0t + ((size_t)h*DH + drow)*S_LEN + key0 + ch*8);
      *(short8*)((char*)Vs + drow*128 + ((ch<<4) ^ ((drow&7)<<4))) = vv;
    }
    __syncthreads();

    // QK^T: sc[nt] = 16q x 16key fragment
    f32x4 sc[4];
    #pragma unroll
    for (int nt=0;nt<4;++nt) sc[nt] = (f32x4){0.f,0.f,0.f,0.f};
    #pragma unroll
    for (int ks=0;ks<4;++ks){
      #pragma unroll
      for (int nt=0;nt<4;++nt){
        int krow = (nt<<4) + lr;
        short8 kf = *(const short8*)((char*)Ks + krow*256 + (((ks<<6)+(lg<<4)) ^ ((krow&7)<<4)));
        sc[nt] = __builtin_amdgcn_mfma_f32_16x16x32_bf16(qf[ks], kf, sc[nt], 0,0,0);
      }
    }

    // scale + causal mask + online softmax (row r lives at reg r, group lg)
    #pragma unroll
    for (int r=0;r<4;++r){
      int qrow = qbase + (lg<<2) + r;
      float vals[4]; float mx = -1e30f;
      #pragma unroll
      for (int nt=0;nt<4;++nt){
        int key = key0 + (nt<<4) + lr;
        float v = sc[nt][r]*SCALE_F;
        if (key > qrow) v = -1e30f;
        vals[nt] = v; mx = fmaxf(mx, v);
      }
      #pragma unroll
      for (int mm=1;mm<16;mm<<=1) mx = fmaxf(mx, __shfl_xor(mx,mm,64));
      float mn = fmaxf(mrow[r], mx);
      float alpha = __expf(mrow[r]-mn);
      float ls = 0.f;
      int qr = (lg<<2)+r;
      #pragma unroll
      for (int nt=0;nt<4;++nt){
        float p = __expf(vals[nt]-mn);
        ls += p;
        *(ushort*)((char*)&Ps[w][0] + ((qr<<7) + (((((nt<<4)+lr))<<1) ^ ((qr&7)<<4)))) = f2bf(p);
      }
      #pragma unroll
      for (int mm=1;mm<16;mm<<=1) ls += __shfl_xor(ls,mm,64);
      lrow[r] = lrow[r]*alpha + ls;
      mrow[r] = mn;
      #pragma unroll
      for (int dt=0;dt<8;++dt) o[dt][r] *= alpha;
    }

    // PV: o[dt] += P(16q x 64key) @ V(64key x 16d), same-wave LDS (no barrier needed)
    #pragma unroll
    for (int ks=0;ks<2;++ks){
      short8 pa = *(const short8*)((char*)&Ps[w][0] + ((lr<<7) + (((ks<<6)+(lg<<4)) ^ ((lr&7)<<4))));
      #pragma unroll
      for (int dt=0;dt<8;++dt){
        int drow = (dt<<4) + lr;
        short8 vb = *(const short8*)((char*)Vs + drow*128 + (((ks<<6)+(lg<<4)) ^ ((drow&7)<<4)));
        o[dt] = __builtin_amdgcn_mfma_f32_16x16x32_bf16(pa, vb, o[dt], 0,0,0);
      }
    }
  }

  // fold extra logits d1,d2 (columns S, S+1), normalize, write bf16
  #pragma unroll
  for (int r=0;r<4;++r){
    int qrow = qbase + (lg<<2) + r;
    float mfin = fmaxf(mrow[r], fmaxf(d1v[r], d2v[r]));
    float alpha = __expf(mrow[r]-mfin);
    float p1 = __expf(d1v[r]-mfin);
    float p2 = __expf(d2v[r]-mfin);
    float linv = 1.0f / (lrow[r]*alpha + p1 + p2);
    const float* v1r = v1c + ((size_t)h*S_LEN + qrow)*DH;
    const float* vpr = vpre + (size_t)qrow*KVDIM + kvh*DH;
    ushort* outr = outb + (size_t)qrow*QDIM + h*DH;
    #pragma unroll
    for (int dt=0;dt<8;++dt){
      int d = (dt<<4) + lr;
      float val = (o[dt][r]*alpha + p1*v1r[d] + p2*vpr[d]) * linv;
      outr[d] = f2bf(val);
    }
  }
}

extern "C" void kernel_launch(void* const* d_in, const int* in_sizes, int n_in,
                              void* d_out, int out_size, void* d_ws, size_t ws_size,
                              hipStream_t stream) {
  const float* X    = (const float*)d_in[0];
  // d_in[1] = attention_mask: exactly the causal mask -> implemented directly
  const int*   pids = (const int*)  d_in[2];
  const float* k0   = (const float*)d_in[3];
  const float* k1   = (const float*)d_in[4];
  const float* v0   = (const float*)d_in[5];
  const float* v1   = (const float*)d_in[6];
  const float* Wq   = (const float*)d_in[7];
  const float* Wk   = (const float*)d_in[8];
  const float* Wv   = (const float*)d_in[9];
  const float* Wo   = (const float*)d_in[10];
  float* out = (float*)d_out;

  // workspace layout (≈180 MB total)
  char* ws = (char*)d_ws;
  ushort* Xb   = (ushort*)(ws);                 // 33554432  [S][8192] bf16
  ushort* WT   = (ushort*)(ws + 33554432);      // 67108864  reused: WqT/WkT/WvT/WoT
  float*  qpre = (float*) (ws + 100663296);     // 33554432  [S][4096] f32
  float*  kpre = (float*) (ws + 134217728);     //  8388608  [S][1024] f32
  float*  vpre = (float*) (ws + 142606336);     //  8388608  [S][1024] f32
  ushort* qbv  = (ushort*)(ws + 150994944);     // 16777216  [S][32][128] bf16
  ushort* kbv  = (ushort*)(ws + 167772160);     //  4194304  [S][8][128] bf16
  ushort* v0t  = (ushort*)(ws + 171966464);     // 16777216  [32][128][S] bf16
  ushort* attnb = (ushort*)qpre;                // alias: qpre dead after rope_q

  dim3 b256(256), b328(32,8);

  // X -> bf16
  cast_f32_bf16<<<16384, b256, 0, stream>>>(X, Xb, (S_LEN*K2H)/4);

  // Q = X @ Wq
  transpose_cast<<<dim3(QDIM/32, K2H/32), b328, 0, stream>>>(Wq, WT, K2H, QDIM);
  gemm_bf16<<<dim3(QDIM/128, S_LEN/128), b256, 0, stream>>>(Xb, WT, qpre, S_LEN, QDIM, K2H);
  // K = X @ Wk
  transpose_cast<<<dim3(KVDIM/32, K2H/32), b328, 0, stream>>>(Wk, WT, K2H, KVDIM);
  gemm_bf16<<<dim3(KVDIM/128, S_LEN/128), b256, 0, stream>>>(Xb, WT, kpre, S_LEN, KVDIM, K2H);
  // V = X @ Wv
  transpose_cast<<<dim3(KVDIM/32, K2H/32), b328, 0, stream>>>(Wv, WT, K2H, KVDIM);
  gemm_bf16<<<dim3(KVDIM/128, S_LEN/128), b256, 0, stream>>>(Xb, WT, vpre, S_LEN, KVDIM, K2H);

  // RoPE + cast to bf16
  rope_cast<<<16384, b256, 0, stream>>>(qpre, pids, qbv, NH,  S_LEN*NH*64);
  rope_cast<<<4096,  b256, 0, stream>>>(kpre, pids, kbv, NKV, S_LEN*NKV*64);

  // V0 transpose for PV B-operand
  transpose_v0<<<dim3(S_LEN/32, DH/32, NH), b328, 0, stream>>>(v0, v0t);

  // attention
  attn_kernel<<<dim3(S_LEN/64, NH), b256, 0, stream>>>(qbv, kbv, k1, v1, k0, v0t, vpre, attnb);

  // out = attn @ Wo
  transpose_cast<<<dim3(QDIM/32, QDIM/32), b328, 0, stream>>>(Wo, WT, QDIM, QDIM);
  gemm_bf16<<<dim3(QDIM/128, S_LEN/128), b256, 0, stream>>>(attnb, WT, out, S_LEN, QDIM, QDIM);
}

// Round 2
// 970.737 us; speedup vs baseline: 1.2217x; 1.2217x over previous
//
#include <hip/hip_runtime.h>

// Problem constants (B=1 fixed)
#define S_LEN 2048
#define NH    32
#define NKV   8
#define DH    128
#define QDIM  4096   // NH*DH
#define KVDIM 1024   // NKV*DH
#define KV2   2048   // KVDIM*2 (K|V concatenated)
#define K2H   8192   // 2*HID
#define NT    32     // S/64 key tiles
#define SCALE_F 0.08838834764831845f  // 128^-0.5

typedef __attribute__((ext_vector_type(8))) short short8;   // 8 bf16 (raw)
typedef __attribute__((ext_vector_type(4))) float f32x4;

__device__ __forceinline__ ushort f2bf(float f){
  union { float f; unsigned u; } x; x.f = f;
  unsigned r = (x.u + 0x7FFFu + ((x.u>>16)&1u)) >> 16;  // RNE, data has no NaN
  return (ushort)r;
}
__device__ __forceinline__ float bf2f(ushort h){
  union { unsigned u; float f; } x; x.u = ((unsigned)h)<<16; return x.f;
}

// async global -> LDS, 16B per lane. LDS dest is wave-uniform base + lane*16.
__device__ __forceinline__ void gload16(const void* g, void* l){
  __builtin_amdgcn_global_load_lds(
      (const __attribute__((address_space(1))) unsigned*)g,
      (__attribute__((address_space(3))) unsigned*)l, 16, 0, 0);
}

// ---------------- elementwise cast f32 -> bf16 (x4 vectorized) ----------------
__global__ void cast_f32_bf16(const float* __restrict__ in, ushort* __restrict__ out, int n4){
  int i = blockIdx.x*256 + threadIdx.x;
  if (i >= n4) return;
  float4 v = ((const float4*)in)[i];
  ushort4 o; o.x=f2bf(v.x); o.y=f2bf(v.y); o.z=f2bf(v.z); o.w=f2bf(v.w);
  ((ushort4*)out)[i] = o;
}

// ---------------- W [K][N] f32 -> WT [N][K] bf16 (64k x 32n tile, ushort2 writes) ----------------
__global__ void transpose_cast(const float* __restrict__ in, ushort* __restrict__ out, int K, int N){
  __shared__ float tile[64][33];
  int n0 = blockIdx.x<<5, k0 = blockIdx.y<<6;
  int tx = threadIdx.x, ty = threadIdx.y;          // (32,8)
  #pragma unroll
  for (int j=0;j<8;++j)
    tile[ty+8*j][tx] = in[(size_t)(k0+ty+8*j)*N + n0 + tx];
  __syncthreads();
  #pragma unroll
  for (int j=0;j<4;++j){
    int c = ty+8*j;                                 // local n
    ushort2 o; o.x = f2bf(tile[2*tx][c]); o.y = f2bf(tile[2*tx+1][c]);
    *(ushort2*)(out + (size_t)(n0+c)*K + k0 + 2*tx) = o;
  }
}

// ---------------- cache_v0 [H][S][D] f32 -> v0t [H][D][S] bf16 ----------------
__global__ void transpose_v0(const float* __restrict__ v0, ushort* __restrict__ v0t){
  __shared__ float tile[32][33];
  int s0 = blockIdx.x<<5, d0 = blockIdx.y<<5, h = blockIdx.z;
  int tx = threadIdx.x, ty = threadIdx.y;          // (32,8)
  #pragma unroll
  for (int j=0;j<4;++j)
    tile[ty+8*j][tx] = v0[((size_t)h*S_LEN + s0+ty+8*j)*DH + d0 + tx];
  __syncthreads();
  #pragma unroll
  for (int j=0;j<4;++j)
    v0t[((size_t)h*DH + d0+ty+8*j)*S_LEN + s0 + tx] = f2bf(tile[tx][ty+8*j]);
}

// ---------------- RoPE + cast: pre [S][istride] f32 cols [h*128..] -> outb bf16 ----------------
__global__ void rope_cast(const float* __restrict__ pre, const int* __restrict__ pids,
                          ushort* __restrict__ outb, int nheads, int istride, int total){
  int idx = blockIdx.x*256 + threadIdx.x;
  if (idx >= total) return;
  int d = idx & 63; int r = idx >> 6;
  int h = r % nheads; int s = r / nheads;
  const float* src = pre + (size_t)s*istride + h*DH;
  float a = src[d], b = src[d+64];
  float pos = (float)(pids[s] + 2);
  float ang = pos * exp2f(-(float)d * 0.20762050593046014f); // 10000^(-d/64)
  float sn, cs; sincosf(ang, &sn, &cs);
  ushort* dst = outb + ((size_t)s*nheads + h)*DH;
  dst[d]      = f2bf(a*cs - b*sn);
  dst[d+64]   = f2bf(b*cs + a*sn);
}

// ---------------- bf16 GEMM: C[M][N] = A[M][K] @ Bt[N][K]^T, fp32 out ----------------
// m97 structure: 128x128 tile, BK=64, 4 waves, global_load_lds width-16,
// linear LDS dest + pre-swizzled global source (rule #21) -> conflict-free ds_read_b128.
__global__ __launch_bounds__(256) void gemm_bf16(
    const ushort* __restrict__ A, const ushort* __restrict__ Bt,
    float* __restrict__ C, int M, int N, int K)
{
  __shared__ __align__(16) ushort As[128*64];
  __shared__ __align__(16) ushort Bs[128*64];
  const int tid = threadIdx.x;
  const int w = tid>>6, lane = tid&63;
  const int wm = w>>1, wn = w&1;
  const int lg = lane>>4, lr = lane&15;
  const int m0 = blockIdx.y<<7, n0 = blockIdx.x<<7;
  // staging: each wave stages 32 rows (4 instrs x 8 rows), 128B/row.
  // LDS[row][c] must hold global chunk c^(row&7); dest is linear, so source
  // chunk for lane (g=lane>>3 rows, c=lane&7 chunks) is c^g  (row&7 == g).
  const int g = lane>>3, cc = lane&7;
  const int sc = (cc ^ g) << 3;                    // element offset in row
  const ushort* Abase = A + (size_t)(m0 + w*32 + g)*K + sc;
  const ushort* Bbase = Bt + (size_t)(n0 + w*32 + g)*K + sc;

  f32x4 acc[4][4];
  #pragma unroll
  for (int mt=0;mt<4;++mt)
    #pragma unroll
    for (int nt=0;nt<4;++nt) acc[mt][nt] = (f32x4){0.f,0.f,0.f,0.f};

  for (int k0=0;k0<K;k0+=64){
    __syncthreads();
    #pragma unroll
    for (int i=0;i<4;++i){
      gload16(Abase + k0 + (size_t)(i*8)*K, As + (w*32 + i*8)*64);
      gload16(Bbase + k0 + (size_t)(i*8)*K, Bs + (w*32 + i*8)*64);
    }
    __syncthreads();   // vmcnt(0) drain -> staged data visible
    #pragma unroll
    for (int ks=0;ks<2;++ks){
      short8 af[4], bfr[4];
      #pragma unroll
      for (int mt=0;mt<4;++mt){
        int row = (wm<<6)+(mt<<4)+lr;
        af[mt] = *(const short8*)((char*)As + row*128 + (((ks<<6)+(lg<<4)) ^ ((lr&7)<<4)));
      }
      #pragma unroll
      for (int nt=0;nt<4;++nt){
        int row = (wn<<6)+(nt<<4)+lr;
        bfr[nt] = *(const short8*)((char*)Bs + row*128 + (((ks<<6)+(lg<<4)) ^ ((lr&7)<<4)));
      }
      #pragma unroll
      for (int mt=0;mt<4;++mt)
        #pragma unroll
        for (int nt=0;nt<4;++nt)
          acc[mt][nt] = __builtin_amdgcn_mfma_f32_16x16x32_bf16(af[mt], bfr[nt], acc[mt][nt], 0,0,0);
    }
  }
  #pragma unroll
  for (int mt=0;mt<4;++mt)
    #pragma unroll
    for (int nt=0;nt<4;++nt)
      #pragma unroll
      for (int r=0;r<4;++r){
        int row = m0 + (wm<<6) + (mt<<4) + (lg<<2) + r;   // C/D: row=(lane>>4)*4+reg
        int col = n0 + (wn<<6) + (nt<<4) + lr;            //      col=lane&15
        C[(size_t)row*N + col] = acc[mt][nt][r];
      }
}

// ---------------- flash attention with 2 extra logit columns ----------------
// grid (NT/2, H); block 256 = 4 waves. Each block processes q-tiles
// {x, NT-1-x}: (x+1) + (NT-x) = NT+1 = 33 key-tile iters per block, uniform.
__global__ __launch_bounds__(256) void attn_kernel(
    const ushort* __restrict__ qb,   // [S][NH][DH] bf16 (roped)
    const ushort* __restrict__ kb,   // [S][NKV][DH] bf16 (roped)
    const float* __restrict__ k1c,   // [NH][S][DH] f32
    const float* __restrict__ v1c,   // [NH][S][DH] f32
    const ushort* __restrict__ k0b,  // [NH][S][DH] bf16
    const ushort* __restrict__ v0t,  // [NH][DH][S] bf16
    const float* __restrict__ vpre,  // [S][KV2] f32, pre-offset to V columns
    ushort* __restrict__ outb)       // [S][NH*DH] bf16
{
  __shared__ __align__(16) ushort Ks[64*128];   // [key][d], swizzled reads, 16KB
  __shared__ __align__(16) ushort Vs[128*64];   // [d][key], swizzled reads, 16KB
  __shared__ __align__(16) ushort Ps[4][16*64]; // per-wave P, 8KB
  const int tid = threadIdx.x;
  const int w = tid>>6, lane = tid&63;
  const int lg = lane>>4, lr = lane&15;
  const int h = blockIdx.y, kvh = h>>2;
  const int g4 = lane>>4, c16 = lane&15;        // K-tile staging (256B rows)
  const int g8 = lane>>3, c8 = lane&7;          // V-tile staging (128B rows)

  for (int rep=0; rep<2; ++rep){
    const int qt = rep ? (NT-1-(int)blockIdx.x) : (int)blockIdx.x;
    const int q0 = qt<<6, qbase = q0 + (w<<4);

    // Q fragments (A operand): row=lane&15, k=(lane>>4)*8 contiguous
    short8 qf[4];
    {
      int row = qbase + lr;
      const ushort* qr = qb + ((size_t)row*NH + h)*DH;
      #pragma unroll
      for (int ks=0;ks<4;++ks) qf[ks] = *(const short8*)(qr + ks*32 + lg*8);
    }

    // d1 = q . cache_k1[h,s] * scale ; d2 = q . k_roped[s,kvh] * scale
    float d1v[4], d2v[4];
    #pragma unroll
    for (int r=0;r<4;++r){
      int row = qbase + (lg<<2) + r;
      const ushort* qr  = qb  + ((size_t)row*NH  + h  )*DH + lr*8;
      const float*  kr1 = k1c + ((size_t)h*S_LEN + row)*DH + lr*8;
      const ushort* kr2 = kb  + ((size_t)row*NKV + kvh)*DH + lr*8;
      float s1=0.f, s2=0.f;
      #pragma unroll
      for (int j=0;j<8;++j){
        float qv = bf2f(qr[j]);
        s1 = fmaf(qv, kr1[j], s1);
        s2 = fmaf(qv, bf2f(kr2[j]), s2);
      }
      #pragma unroll
      for (int mm=1;mm<16;mm<<=1){ s1 += __shfl_xor(s1,mm,64); s2 += __shfl_xor(s2,mm,64); }
      d1v[r] = s1*SCALE_F; d2v[r] = s2*SCALE_F;
    }

    f32x4 o[8];
    #pragma unroll
    for (int dt=0;dt<8;++dt) o[dt] = (f32x4){0.f,0.f,0.f,0.f};
    float mrow[4], lrow[4];
    #pragma unroll
    for (int r=0;r<4;++r){ mrow[r] = -1e30f; lrow[r] = 0.f; }

    const int ntiles = qt + 1;     // causal: keys 0 .. q0+63
    for (int kt=0; kt<ntiles; ++kt){
      const int key0 = kt<<6;
      __syncthreads();
      // K tile [64 key][128 d] bf16 via global_load_lds, pre-swizzled source
      #pragma unroll
      for (int i=0;i<4;++i){
        int row = (w<<4) + (i<<2) + g4;             // row&7 == ((i<<2)+g4)&7
        int scol = (c16 ^ (((i<<2)+g4)&7)) << 3;
        gload16(k0b + ((size_t)h*S_LEN + key0 + row)*DH + scol,
                Ks + ((w<<4)+(i<<2))*128);
      }
      // V tile [128 d][64 key] bf16, 128B rows: row&7 == g8
      #pragma unroll
      for (int i=0;i<4;++i){
        int row = (w<<5) + (i<<3) + g8;
        int scol = (c8 ^ g8) << 3;
        gload16(v0t + ((size_t)h*DH + row)*S_LEN + key0 + scol,
                Vs + ((w<<5)+(i<<3))*64);
      }
      __syncthreads();

      // QK^T: sc[nt] = 16q x 16key fragment
      f32x4 sc[4];
      #pragma unroll
      for (int nt=0;nt<4;++nt) sc[nt] = (f32x4){0.f,0.f,0.f,0.f};
      #pragma unroll
      for (int ks=0;ks<4;++ks){
        #pragma unroll
        for (int nt=0;nt<4;++nt){
          int krow = (nt<<4) + lr;
          short8 kf = *(const short8*)((char*)Ks + krow*256 + (((ks<<6)+(lg<<4)) ^ ((krow&7)<<4)));
          sc[nt] = __builtin_amdgcn_mfma_f32_16x16x32_bf16(qf[ks], kf, sc[nt], 0,0,0);
        }
      }

      // scale + causal mask + online softmax
      #pragma unroll
      for (int r=0;r<4;++r){
        int qrow = qbase + (lg<<2) + r;
        float vals[4]; float mx = -1e30f;
        #pragma unroll
        for (int nt=0;nt<4;++nt){
          int key = key0 + (nt<<4) + lr;
          float v = sc[nt][r]*SCALE_F;
          if (key > qrow) v = -1e30f;
          vals[nt] = v; mx = fmaxf(mx, v);
        }
        #pragma unroll
        for (int mm=1;mm<16;mm<<=1) mx = fmaxf(mx, __shfl_xor(mx,mm,64));
        float mn = fmaxf(mrow[r], mx);
        float alpha = __expf(mrow[r]-mn);
        float ls = 0.f;
        int qr = (lg<<2)+r;
        #pragma unroll
        for (int nt=0;nt<4;++nt){
          float p = __expf(vals[nt]-mn);
          ls += p;
          *(ushort*)((char*)&Ps[w][0] + ((qr<<7) + ((((nt<<4)+lr)<<1) ^ ((qr&7)<<4)))) = f2bf(p);
        }
        #pragma unroll
        for (int mm=1;mm<16;mm<<=1) ls += __shfl_xor(ls,mm,64);
        lrow[r] = lrow[r]*alpha + ls;
        mrow[r] = mn;
        #pragma unroll
        for (int dt=0;dt<8;++dt) o[dt][r] *= alpha;
      }

      // PV: o[dt] += P(16q x 64key) @ V(64key x 16d); same-wave LDS
      #pragma unroll
      for (int ks=0;ks<2;++ks){
        short8 pa = *(const short8*)((char*)&Ps[w][0] + ((lr<<7) + (((ks<<6)+(lg<<4)) ^ ((lr&7)<<4))));
        #pragma unroll
        for (int dt=0;dt<8;++dt){
          int drow = (dt<<4) + lr;
          short8 vb = *(const short8*)((char*)Vs + drow*128 + (((ks<<6)+(lg<<4)) ^ ((drow&7)<<4)));
          o[dt] = __builtin_amdgcn_mfma_f32_16x16x32_bf16(pa, vb, o[dt], 0,0,0);
        }
      }
    }

    // fold extra logits d1,d2, normalize, write bf16
    #pragma unroll
    for (int r=0;r<4;++r){
      int qrow = qbase + (lg<<2) + r;
      float mfin = fmaxf(mrow[r], fmaxf(d1v[r], d2v[r]));
      float alpha = __expf(mrow[r]-mfin);
      float p1 = __expf(d1v[r]-mfin);
      float p2 = __expf(d2v[r]-mfin);
      float linv = 1.0f / (lrow[r]*alpha + p1 + p2);
      const float* v1r = v1c + ((size_t)h*S_LEN + qrow)*DH;
      const float* vpr = vpre + (size_t)qrow*KV2 + kvh*DH;
      ushort* outr = outb + (size_t)qrow*QDIM + h*DH;
      #pragma unroll
      for (int dt=0;dt<8;++dt){
        int d = (dt<<4) + lr;
        float val = (o[dt][r]*alpha + p1*v1r[d] + p2*vpr[d]) * linv;
        outr[d] = f2bf(val);
      }
    }
  }
}

extern "C" void kernel_launch(void* const* d_in, const int* in_sizes, int n_in,
                              void* d_out, int out_size, void* d_ws, size_t ws_size,
                              hipStream_t stream) {
  const float* X    = (const float*)d_in[0];
  // d_in[1] = attention_mask: exactly the causal mask -> implemented directly
  const int*   pids = (const int*)  d_in[2];
  const float* k0   = (const float*)d_in[3];
  const float* k1   = (const float*)d_in[4];
  const float* v0   = (const float*)d_in[5];
  const float* v1   = (const float*)d_in[6];
  const float* Wq   = (const float*)d_in[7];
  const float* Wk   = (const float*)d_in[8];
  const float* Wv   = (const float*)d_in[9];
  const float* Wo   = (const float*)d_in[10];
  float* out = (float*)d_out;

  // workspace layout (peak 188.7 MB, same as round 1)
  char* ws = (char*)d_ws;
  ushort* Xb    = (ushort*)(ws);                  // [2048][8192] bf16, 33.5MB
  ushort* WT0   = (ushort*)(ws + 33554432);       // WqT [4096][8192] 67MB; later WkvT [2048][8192] 33.5MB
  ushort* k0b   = WT0;                            // alias: after KV gemm, [32][2048][128] bf16 16.8MB
  ushort* WoT   = (ushort*)(ws + 67108864);       // [4096][4096] bf16 33.5MB (after WqT dead)
  float*  qpre  = (float*) (ws + 100663296);      // [2048][4096] f32 33.5MB
  float*  kvpre = (float*) (ws + 134217728);      // [2048][2048] f32 16.8MB (K|V)
  ushort* qbv   = (ushort*)(ws + 150994944);      // [2048][32][128] bf16 16.8MB
  ushort* kbv   = (ushort*)(ws + 167772160);      // [2048][8][128] bf16 4.2MB
  ushort* v0t   = (ushort*)(ws + 171966464);      // [32][128][2048] bf16 16.8MB
  ushort* attnb = (ushort*)qpre;                  // alias: qpre dead after rope_q

  dim3 b256(256), b328(32,8);

  // X -> bf16
  cast_f32_bf16<<<16384, b256, 0, stream>>>(X, Xb, (S_LEN*K2H)/4);

  // Q = X @ Wq
  transpose_cast<<<dim3(QDIM/32, K2H/64), b328, 0, stream>>>(Wq, WT0, K2H, QDIM);
  gemm_bf16<<<dim3(QDIM/128, S_LEN/128), b256, 0, stream>>>(Xb, WT0, qpre, S_LEN, QDIM, K2H);

  // [K|V] = X @ [Wk|Wv]  (N=2048)
  transpose_cast<<<dim3(KVDIM/32, K2H/64), b328, 0, stream>>>(Wk, WT0, K2H, KVDIM);
  transpose_cast<<<dim3(KVDIM/32, K2H/64), b328, 0, stream>>>(Wv, WT0 + (size_t)KVDIM*K2H, K2H, KVDIM);
  gemm_bf16<<<dim3(KV2/128, S_LEN/128), b256, 0, stream>>>(Xb, WT0, kvpre, S_LEN, KV2, K2H);

  // k0 -> bf16 (overwrites WkvT, dead after KV gemm)
  cast_f32_bf16<<<8192, b256, 0, stream>>>(k0, k0b, (NH*S_LEN*DH)/4);

  // Wo transpose (into region after WkvT/k0b)
  transpose_cast<<<dim3(QDIM/32, QDIM/64), b328, 0, stream>>>(Wo, WoT, QDIM, QDIM);

  // RoPE + cast to bf16
  rope_cast<<<16384, b256, 0, stream>>>(qpre,  pids, qbv, NH,  QDIM, S_LEN*NH*64);
  rope_cast<<<4096,  b256, 0, stream>>>(kvpre, pids, kbv, NKV, KV2,  S_LEN*NKV*64);

  // V0 transpose for PV B-operand
  transpose_v0<<<dim3(S_LEN/32, DH/32, NH), b328, 0, stream>>>(v0, v0t);

  // attention (load-balanced q-tile pairs)
  attn_kernel<<<dim3(NT/2, NH), b256, 0, stream>>>(qbv, kbv, k1, v1, k0b, v0t,
                                                   kvpre + KVDIM, attnb);

  // out = attn @ Wo
  gemm_bf16<<<dim3(QDIM/128, S_LEN/128), b256, 0, stream>>>(attnb, WoT, out, S_LEN, QDIM, QDIM);
}